// Round 2
// baseline (639.611 us; speedup 1.0000x reference)
//
#include <hip/hip_runtime.h>

// 3x3 reflect-padded patch extraction.
// x: [8, 256, 256, 32] f32  ->  out: [8, 256, 256, 288] f32
// out[b,h,w, c*9 + i] = x[b, refl(h + i/3 - 1), refl(w + i%3 - 1), c]
//
// Two-phase LDS scheme: stage input tile -> compile-time tap gather into an
// output-layout LDS tile (all b128, imm offsets) -> linear coalesced store.

#define BB 8
#define HH 256
#define WW 256
#define CC 32
#define TAPS 9
#define OUTC (CC * TAPS)    // 288
#define TW 32               // w-tile per block
#define NTW (WW / TW)       // 8 tiles per row

__device__ __forceinline__ int refl(int i, int n) {
    // np.pad mode='reflect', valid for i in [-1, n]
    return i < 0 ? -i : (i >= n ? 2 * n - 2 - i : i);
}

__global__ __launch_bounds__(256) void patch3x3_v2(
    const float* __restrict__ x, float* __restrict__ out) {
    const int blk = blockIdx.x;
    const int wt = blk % NTW;
    const int h  = (blk / NTW) % HH;
    const int b  = blk / (NTW * HH);
    const int w0 = wt * TW;
    const int t  = threadIdx.x;

    __shared__ float in_lds[3][TW + 2][CC];     // 13056 B
    __shared__ float out_lds[TW][OUTC];         // 36864 B  (total 49920 B)

    // ---- Phase A: stage global -> LDS (coalesced float4) ----
    const int nload4 = 3 * (TW + 2) * (CC / 4); // 816
    for (int idx = t; idx < nload4; idx += 256) {
        const int c4 = idx % (CC / 4);
        const int wl = (idx / (CC / 4)) % (TW + 2);
        const int r  = idx / ((CC / 4) * (TW + 2));
        const int gh = refl(h + r - 1, HH);
        const int gw = refl(w0 + wl - 1, WW);
        const float4* src =
            (const float4*)(x + (((b * HH + gh) * WW + gw) * CC)) + c4;
        *((float4*)&in_lds[r][wl][0] + c4) = *src;
    }
    __syncthreads();

    // ---- Phase B: compile-time tap gather, b128 in / b128 out ----
    {
        const int p  = t >> 3;      // pixel in tile, 0..31
        const int cg = t & 7;       // channel group of 4, 0..7
        float4 q[3][3];
#pragma unroll
        for (int ki = 0; ki < 3; ++ki)
#pragma unroll
            for (int kj = 0; kj < 3; ++kj)
                q[ki][kj] = *(const float4*)&in_lds[ki][p + kj][cg * 4];

        // 36 output floats for this (p, cg): local flat f = cl*9 + i,
        // cl = c - 4*cg in [0,4), i = 3*ki + kj.
#pragma unroll
        for (int m = 0; m < 9; ++m) {
            float4 v;
#pragma unroll
            for (int k = 0; k < 4; ++k) {
                const int f  = 4 * m + k;   // compile-time
                const int cl = f / 9;
                const int i  = f % 9;
                const int ki = i / 3;
                const int kj = i % 3;
                ((float*)&v)[k] = ((const float*)&q[ki][kj])[cl];
            }
            *(float4*)&out_lds[p][cg * 36 + 4 * m] = v;
        }
    }
    __syncthreads();

    // ---- Phase C: linear coalesced store of the out tile ----
    float4* outp = (float4*)(out + (size_t)((b * HH + h) * WW + w0) * OUTC);
    const float4* src4 = (const float4*)&out_lds[0][0];
#pragma unroll
    for (int it = 0; it < (TW * OUTC / 4) / 256; ++it) {  // 9 iters
        const int idx = t + 256 * it;
        outp[idx] = src4[idx];
    }
}

extern "C" void kernel_launch(void* const* d_in, const int* in_sizes, int n_in,
                              void* d_out, int out_size, void* d_ws, size_t ws_size,
                              hipStream_t stream) {
    const float* x = (const float*)d_in[0];
    float* out = (float*)d_out;
    const int nblocks = BB * HH * NTW;   // 16384
    patch3x3_v2<<<nblocks, 256, 0, stream>>>(x, out);
}

// Round 3
// 619.369 us; speedup vs baseline: 1.0327x; 1.0327x over previous
//
#include <hip/hip_runtime.h>

// 3x3 reflect-padded patch extraction.
// x: [8, 256, 256, 32] f32  ->  out: [8, 256, 256, 288] f32
// out[b,h,w, c*9 + i] = x[b, refl(h + i/3 - 1), refl(w + i%3 - 1), c]
//
// v3: no input LDS stage — 9 tap loads/thread straight from global (L1-hot,
// coalesced ~1KB/wave-load). Single LDS transpose into output layout
// (all b128, imm offsets), one barrier, then linear coalesced float4 stores.

#define BB 8
#define HH 256
#define WW 256
#define CC 32
#define TAPS 9
#define OUTC (CC * TAPS)    // 288
#define TW 32               // w-tile per block
#define NTW (WW / TW)       // 8 tiles per row

__device__ __forceinline__ int refl(int i, int n) {
    // np.pad mode='reflect', valid for i in [-1, n]
    return i < 0 ? -i : (i >= n ? 2 * n - 2 - i : i);
}

__global__ __launch_bounds__(256) void patch3x3_v3(
    const float* __restrict__ x, float* __restrict__ out) {
    const int blk = blockIdx.x;
    const int wt = blk % NTW;
    const int h  = (blk / NTW) % HH;
    const int b  = blk / (NTW * HH);
    const int w0 = wt * TW;
    const int t  = threadIdx.x;

    __shared__ float out_lds[TW][OUTC];         // 36864 B

    // ---- tap gather straight from global (wave-uniform row bases) ----
    const float* xb = x + (size_t)b * HH * WW * CC;
    const float* row0 = xb + (size_t)refl(h - 1, HH) * WW * CC;
    const float* row1 = xb + (size_t)h * WW * CC;
    const float* row2 = xb + (size_t)refl(h + 1, HH) * WW * CC;

    const int p  = t >> 3;      // pixel in tile, 0..31
    const int cg = t & 7;       // channel group of 4, 0..7

    int coff[3];
#pragma unroll
    for (int kj = 0; kj < 3; ++kj)
        coff[kj] = refl(w0 + p + kj - 1, WW) * CC + cg * 4;

    float4 q[3][3];
#pragma unroll
    for (int kj = 0; kj < 3; ++kj) {
        q[0][kj] = *(const float4*)(row0 + coff[kj]);
        q[1][kj] = *(const float4*)(row1 + coff[kj]);
        q[2][kj] = *(const float4*)(row2 + coff[kj]);
    }

    // ---- repack (pure register selects) + LDS write in output layout ----
    // local flat f = cl*9 + i, cl in [0,4), i = 3*ki + kj
#pragma unroll
    for (int m = 0; m < 9; ++m) {
        float4 v;
#pragma unroll
        for (int k = 0; k < 4; ++k) {
            const int f  = 4 * m + k;   // compile-time
            const int cl = f / 9;
            const int i  = f % 9;
            const int ki = i / 3;
            const int kj = i % 3;
            ((float*)&v)[k] = ((const float*)&q[ki][kj])[cl];
        }
        *(float4*)&out_lds[p][cg * 36 + 4 * m] = v;
    }
    __syncthreads();

    // ---- linear coalesced store of the out tile ----
    float4* outp = (float4*)(out + (size_t)((b * HH + h) * WW + w0) * OUTC);
    const float4* src4 = (const float4*)&out_lds[0][0];
#pragma unroll
    for (int it = 0; it < (TW * OUTC / 4) / 256; ++it) {  // 9 iters
        const int idx = t + 256 * it;
        outp[idx] = src4[idx];
    }
}

extern "C" void kernel_launch(void* const* d_in, const int* in_sizes, int n_in,
                              void* d_out, int out_size, void* d_ws, size_t ws_size,
                              hipStream_t stream) {
    const float* x = (const float*)d_in[0];
    float* out = (float*)d_out;
    const int nblocks = BB * HH * NTW;   // 16384
    patch3x3_v3<<<nblocks, 256, 0, stream>>>(x, out);
}